// Round 1
// baseline (458.741 us; speedup 1.0000x reference)
//
#include <hip/hip_runtime.h>
#include <hip/hip_bf16.h>

// ModulatedConv (StyleGAN2 conv_transpose2d stride=2, K=3) on gfx950.
// out[b,o,y,x] = inv[b,o] * sum_{i,ky,kx} (scale_w*weight[o,i,ky,kx]) * (s[b,i]*x[b,i,h,w])
//   with y=2h+ky, x=2w+kx.  Weight is batch-independent after folding s into x
//   and demod into the epilogue.  4 output phases (y%2,x%2), taps {4,2,2,1},
//   shifted-B sharing; bf16 MFMA 16x16x32, fp32 accumulate.

typedef __attribute__((ext_vector_type(8))) short short8;
typedef __attribute__((ext_vector_type(4))) float floatx4;

#define CIN   512
#define COUT  512
#define NB    16
#define HH    32
#define OW    65
#define NSITE 1089     // 33*33 sites (u,v), out y=2u+py, x=2v+px
#define XSTR  40       // LDS k-stride in bf16 elements (80B: 16B-aligned, 2-way banks only)
#define WROWS 128      // o-rows staged per tap

// phase p = py*2+px. taps: global tap id t = ky*3+kx, shift offset into Xl:
//   shift(dh,dw) in {0,-1}^2 -> ((dh+1)*34+(dw+1))*XSTR
__device__ __constant__ int g_ntaps[4]   = {4, 2, 2, 1};
__device__ __constant__ int g_tapt[16]   = {0,2,6,8,  1,7,0,0,  3,5,0,0,  4,0,0,0};
__device__ __constant__ int g_tapoff[16] = {35*XSTR,34*XSTR,XSTR,0,
                                            35*XSTR,XSTR,0,0,
                                            35*XSTR,34*XSTR,0,0,
                                            35*XSTR,0,0,0};

// ---- prep kernels ------------------------------------------------------

// s[b,i] = (1/16) * dot(w[b,:], lin_w[i,:]) + lin_b[i]      (sqrt(2/512)=1/16)
__global__ void k_s(const float* __restrict__ w, const float* __restrict__ lin_w,
                    const float* __restrict__ lin_b, float* __restrict__ s)
{
    int i = blockIdx.x * 256 + threadIdx.x;   // 0..511
    int b = blockIdx.y;
    const float* wr = w + b * 512;
    const float* lr = lin_w + (size_t)i * 512;
    float acc = 0.f;
    for (int d = 0; d < 512; d += 4) {
        float4 a = *(const float4*)(wr + d);
        float4 c = *(const float4*)(lr + d);
        acc += a.x*c.x + a.y*c.y + a.z*c.z + a.w*c.w;
    }
    s[b * 512 + i] = acc * 0.0625f + lin_b[i];
}

// q[o*512+i] = sum_kk weight[o,i,kk]^2
__global__ void k_q(const float* __restrict__ weight, float* __restrict__ q)
{
    int idx = blockIdx.x * 256 + threadIdx.x;   // < 262144
    const float* p = weight + (size_t)idx * 9;
    float acc = 0.f;
#pragma unroll
    for (int j = 0; j < 9; ++j) acc += p[j] * p[j];
    q[idx] = acc;
}

// inv[b,o] = 1/sqrt(scale_w^2 * sum_i s[b,i]^2 q[o,i] + 1e-8),  scale_w^2 = 1/2304
__global__ void k_inv(const float* __restrict__ s, const float* __restrict__ q,
                      float* __restrict__ inv)
{
    int idx = blockIdx.x * 256 + threadIdx.x;   // b*512+o, < 8192
    int b = idx >> 9;
    int o = idx & 511;
    const float* sp = s + b * 512;
    const float* qp = q + (size_t)o * 512;
    float acc = 0.f;
    for (int i = 0; i < 512; i += 4) {
        float4 sv = *(const float4*)(sp + i);
        float4 qv = *(const float4*)(qp + i);
        acc += sv.x*sv.x*qv.x + sv.y*sv.y*qv.y + sv.z*sv.z*qv.z + sv.w*sv.w*qv.w;
    }
    inv[idx] = 1.0f / sqrtf(acc * (1.0f / 2304.0f) + 1e-8f);
}

// wT[t][o][i] = bf16(weight[o,i,t] / 48)     (scale_w = sqrt(2/4608) = 1/48)
__global__ void k_wprep(const float* __restrict__ weight, __hip_bfloat16* __restrict__ wT)
{
    int idx = blockIdx.x * 256 + threadIdx.x;   // < 9*512*512
    int t   = idx / 262144;
    int rem = idx - t * 262144;                 // o*512+i
    float v = weight[(size_t)rem * 9 + t] * (1.0f / 48.0f);
    wT[idx] = __float2bfloat16(v);
}

// xm[b][h][w][i] = bf16(s[b,i] * x[b,i,h,w])  -- channel-minor via LDS transpose
__global__ void k_xprep(const float* __restrict__ x, const float* __restrict__ s,
                        __hip_bfloat16* __restrict__ xm)
{
    __shared__ float tile[32][33];
    int i0 = blockIdx.x * 32;
    int h  = blockIdx.y;
    int b  = blockIdx.z;
    int tw = threadIdx.x & 31;
    int ti = threadIdx.x >> 5;   // 0..7
#pragma unroll
    for (int r = 0; r < 4; ++r) {
        int il = ti + r * 8;
        int i  = i0 + il;
        tile[il][tw] = x[(((size_t)b * 512 + i) * 32 + h) * 32 + tw] * s[b * 512 + i];
    }
    __syncthreads();
#pragma unroll
    for (int r = 0; r < 4; ++r) {
        int wc = ti + r * 8;
        xm[(((size_t)b * 32 + h) * 32 + wc) * 512 + i0 + tw] = __float2bfloat16(tile[tw][wc]);
    }
}

// ---- main conv kernel --------------------------------------------------
// grid: (site_tile 0..8, phase*4+o_tile 0..15, b 0..15), block 256 = 4 waves.
// Block tile: M=128 o's, N=128 flattened sites, K-loop over 512 in chunks of 32.
// Wave (wm,wn) owns 64x64 quadrant: 4 m-frags x 4 n-frags of 16x16.
__global__ __launch_bounds__(256, 2)
void conv_main(const __hip_bfloat16* __restrict__ wT,
               const __hip_bfloat16* __restrict__ xm,
               const float* __restrict__ inv,
               float* __restrict__ out)
{
    __shared__ short Wl[4 * WROWS * XSTR];   // 4 taps x 128 rows x 40  = 40960 B
    __shared__ short Xl[204 * XSTR];         // 6 rows x 34 cols sites  = 16320 B

    const int tid  = threadIdx.x;
    const int lane = tid & 63;
    const int wv   = tid >> 6;
    const int wm   = wv & 1;       // m half
    const int wn   = wv >> 1;      // n half
    const int quad = lane >> 4;
    const int c16  = lane & 15;

    const int site_tile = blockIdx.x;
    const int phase     = blockIdx.y >> 2;
    const int o_tile    = blockIdx.y & 3;
    const int b         = blockIdx.z;

    const int s0     = site_tile * 128;
    const int u_base = s0 / 33;
    const int o_base = o_tile * 128;
    const int ntaps  = g_ntaps[phase];

    // B-operand base LDS offsets (at shift (-1,-1)); tap adds g_tapoff.
    int xbase[4];
#pragma unroll
    for (int f = 0; f < 4; ++f) {
        int site = s0 + wn * 64 + f * 16 + c16;
        int u = site / 33;
        int v = site - u * 33;
        xbase[f] = ((u - u_base) * 34 + v) * XSTR + quad * 8;
    }
    int abase[4];
#pragma unroll
    for (int a = 0; a < 4; ++a)
        abase[a] = (wm * 64 + a * 16 + c16) * XSTR + quad * 8;

    floatx4 acc[4][4];
#pragma unroll
    for (int a = 0; a < 4; ++a)
#pragma unroll
        for (int f = 0; f < 4; ++f)
            acc[a][f] = (floatx4){0.f, 0.f, 0.f, 0.f};

    for (int kc = 0; kc < 16; ++kc) {
        const int k0 = kc * 32;
        // stage W taps: ntaps x 128 rows x 32 k  (16B chunks)
        for (int t = 0; t < ntaps; ++t) {
            const int tgt = g_tapt[phase * 4 + t];
            const __hip_bfloat16* wsrc = wT + ((size_t)tgt * COUT + o_base) * CIN + k0;
#pragma unroll
            for (int j = 0; j < 2; ++j) {
                int ch  = tid + j * 256;          // 0..511
                int row = ch >> 2, k4 = ch & 3;
                uint4 vv = *(const uint4*)(wsrc + (size_t)row * CIN + k4 * 8);
                *(uint4*)(&Wl[t * WROWS * XSTR + row * XSTR + k4 * 8]) = vv;
            }
        }
        // stage X halo tile: rows u_base-1..u_base+4, cols -1..32, zeros OOB
        for (int ch = tid; ch < 816; ch += 256) {
            int slot = ch >> 2, k4 = ch & 3;
            int r = slot / 34;
            int c = slot - r * 34;
            int h = u_base - 1 + r;
            int w = c - 1;
            uint4 vv = {0u, 0u, 0u, 0u};
            if (h >= 0 && h < HH && w >= 0 && w < HH)
                vv = *(const uint4*)(xm + (((size_t)b * HH + h) * HH + w) * CIN + k0 + k4 * 8);
            *(uint4*)(&Xl[slot * XSTR + k4 * 8]) = vv;
        }
        __syncthreads();

        for (int t = 0; t < ntaps; ++t) {
            const int toff = g_tapoff[phase * 4 + t];
            const short* wbase = &Wl[t * WROWS * XSTR];
            short8 A0 = *(const short8*)(wbase + abase[0]);
            short8 A1 = *(const short8*)(wbase + abase[1]);
            short8 A2 = *(const short8*)(wbase + abase[2]);
            short8 A3 = *(const short8*)(wbase + abase[3]);
#pragma unroll
            for (int f = 0; f < 4; ++f) {
                short8 Bf = *(const short8*)(&Xl[xbase[f] + toff]);
                acc[0][f] = __builtin_amdgcn_mfma_f32_16x16x32_bf16(A0, Bf, acc[0][f], 0, 0, 0);
                acc[1][f] = __builtin_amdgcn_mfma_f32_16x16x32_bf16(A1, Bf, acc[1][f], 0, 0, 0);
                acc[2][f] = __builtin_amdgcn_mfma_f32_16x16x32_bf16(A2, Bf, acc[2][f], 0, 0, 0);
                acc[3][f] = __builtin_amdgcn_mfma_f32_16x16x32_bf16(A3, Bf, acc[3][f], 0, 0, 0);
            }
        }
        __syncthreads();
    }

    // epilogue: D col=lane&15 -> site, row=quad*4+reg -> o.  scale by inv[b,o].
    const int py = phase >> 1, px = phase & 1;
#pragma unroll
    for (int a = 0; a < 4; ++a) {
        const int ob = o_base + wm * 64 + a * 16 + quad * 4;
        float iv[4];
#pragma unroll
        for (int r = 0; r < 4; ++r) iv[r] = inv[b * COUT + ob + r];
#pragma unroll
        for (int f = 0; f < 4; ++f) {
            int site = s0 + wn * 64 + f * 16 + c16;
            if (site < NSITE) {
                int u = site / 33;
                int v = site - u * 33;
                int y  = 2 * u + py;
                int xq = 2 * v + px;
                if (y < OW && xq < OW) {
#pragma unroll
                    for (int r = 0; r < 4; ++r)
                        out[(((size_t)b * COUT + ob + r) * OW + y) * OW + xq] =
                            acc[a][f][r] * iv[r];
                }
            }
        }
    }
}

// ---- launcher ----------------------------------------------------------
extern "C" void kernel_launch(void* const* d_in, const int* in_sizes, int n_in,
                              void* d_out, int out_size, void* d_ws, size_t ws_size,
                              hipStream_t stream)
{
    const float* x      = (const float*)d_in[0];   // (16,512,32,32)
    const float* w      = (const float*)d_in[1];   // (16,512)
    const float* weight = (const float*)d_in[2];   // (1,512,512,3,3)
    const float* lin_w  = (const float*)d_in[3];   // (512,512)
    const float* lin_b  = (const float*)d_in[4];   // (512,)
    float* out = (float*)d_out;                    // (16,512,65,65)

    char* ws = (char*)d_ws;
    float* s_buf   = (float*)(ws);                 //   32 KB
    float* inv_buf = (float*)(ws + 32768);         //   32 KB
    float* q_buf   = (float*)(ws + 65536);         //    1 MB
    __hip_bfloat16* wT = (__hip_bfloat16*)(ws + 1114112);   // 4.72 MB: [9][512][512]
    __hip_bfloat16* xm = (__hip_bfloat16*)(ws + 5832704);   // 16.8 MB: [16][32][32][512]

    k_s    <<<dim3(2, 16),     256, 0, stream>>>(w, lin_w, lin_b, s_buf);
    k_q    <<<1024,            256, 0, stream>>>(weight, q_buf);
    k_inv  <<<32,              256, 0, stream>>>(s_buf, q_buf, inv_buf);
    k_wprep<<<9216,            256, 0, stream>>>(weight, wT);
    k_xprep<<<dim3(16, 32, 16),256, 0, stream>>>(x, s_buf, xm);
    conv_main<<<dim3(9, 16, 16), 256, 0, stream>>>(wT, xm, inv_buf, out);
}

// Round 2
// 410.378 us; speedup vs baseline: 1.1179x; 1.1179x over previous
//
#include <hip/hip_runtime.h>
#include <hip/hip_bf16.h>

// ModulatedConv (StyleGAN2 conv_transpose2d stride=2, K=3) on gfx950.
// out[b,o,y,x] = inv[b,o] * sum_{i,ky,kx} (scale_w*weight[o,i,ky,kx]) * (s[b,i]*x[b,i,h,w])
// Round 2: async global_load_lds width-16 staging, 48KB LDS -> 3 blocks/CU,
// XOR k-slot swizzle (2-way banks only), zero-halo padded xm, phase-templated
// body (compile-time tap tables), fused weight prep.

typedef __attribute__((ext_vector_type(8))) short short8;
typedef __attribute__((ext_vector_type(4))) float floatx4;

#define CIN   512
#define COUT  512
#define HH    32
#define OW    65
#define NSITE 1089     // 33*33 sites (u,v); out y=2u+py, x=2v+px

__device__ __forceinline__ void gload16(const void* g, void* l) {
    __builtin_amdgcn_global_load_lds(
        (const __attribute__((address_space(1))) void*)g,
        (__attribute__((address_space(3))) void*)l, 16, 0, 0);
}

// ---- prep kernels ------------------------------------------------------

// s[b,i] = (1/16) * dot(w[b,:], lin_w[i,:]) + lin_b[i]
__global__ void k_s(const float* __restrict__ w, const float* __restrict__ lin_w,
                    const float* __restrict__ lin_b, float* __restrict__ s)
{
    int i = blockIdx.x * 256 + threadIdx.x;
    int b = blockIdx.y;
    const float* wr = w + b * 512;
    const float* lr = lin_w + (size_t)i * 512;
    float acc = 0.f;
    for (int d = 0; d < 512; d += 4) {
        float4 a = *(const float4*)(wr + d);
        float4 c = *(const float4*)(lr + d);
        acc += a.x*c.x + a.y*c.y + a.z*c.z + a.w*c.w;
    }
    s[b * 512 + i] = acc * 0.0625f + lin_b[i];
}

// fused: q[o,i] = sum_kk weight[o,i,kk]^2 ; wT[t][o][i] = bf16(weight[o,i,t]/48)
__global__ void k_wq(const float* __restrict__ weight,
                     __hip_bfloat16* __restrict__ wT, float* __restrict__ q)
{
    int idx = blockIdx.x * 256 + threadIdx.x;   // o*512+i, < 262144
    const float* p = weight + (size_t)idx * 9;
    float v[9], acc = 0.f;
#pragma unroll
    for (int j = 0; j < 9; ++j) { v[j] = p[j]; acc += v[j] * v[j]; }
    q[idx] = acc;
#pragma unroll
    for (int t = 0; t < 9; ++t)
        wT[t * 262144 + idx] = __float2bfloat16(v[t] * (1.0f / 48.0f));
}

// inv[b,o] = 1/sqrt((1/2304) * sum_i s[b,i]^2 q[o,i] + 1e-8)
__global__ void k_inv(const float* __restrict__ s, const float* __restrict__ q,
                      float* __restrict__ inv)
{
    int idx = blockIdx.x * 256 + threadIdx.x;   // b*512+o
    int b = idx >> 9;
    int o = idx & 511;
    const float* sp = s + b * 512;
    const float* qp = q + (size_t)o * 512;
    float acc = 0.f;
    for (int i = 0; i < 512; i += 4) {
        float4 sv = *(const float4*)(sp + i);
        float4 qv = *(const float4*)(qp + i);
        acc += sv.x*sv.x*qv.x + sv.y*sv.y*qv.y + sv.z*sv.z*qv.z + sv.w*sv.w*qv.w;
    }
    inv[idx] = 1.0f / sqrtf(acc * (1.0f / 2304.0f) + 1e-8f);
}

// zero the halo border of xmp [16][34][34][512]
__global__ void k_zero(__hip_bfloat16* __restrict__ xmp)
{
    int idx = blockIdx.x * 256 + threadIdx.x;   // < 16*132*64
    int kc = idx & 63;
    int j  = (idx >> 6) % 132;
    int b  = (idx >> 6) / 132;
    int r, c;
    if (j < 34)       { r = 0;          c = j; }
    else if (j < 68)  { r = 33;         c = j - 34; }
    else if (j < 100) { r = j - 68 + 1; c = 0; }
    else              { r = j - 100 + 1; c = 33; }
    uint4 z = {0u, 0u, 0u, 0u};
    *(uint4*)(xmp + (((size_t)b * 34 + r) * 34 + c) * 512 + kc * 8) = z;
}

// xmp[b][h+1][w+1][i] = bf16(s[b,i] * x[b,i,h,w])   (channel-minor, padded halo)
__global__ void k_xprep(const float* __restrict__ x, const float* __restrict__ s,
                        __hip_bfloat16* __restrict__ xmp)
{
    __shared__ float tile[32][33];
    int i0 = blockIdx.x * 32;
    int h  = blockIdx.y;
    int b  = blockIdx.z;
    int tw = threadIdx.x & 31;
    int ti = threadIdx.x >> 5;
#pragma unroll
    for (int r = 0; r < 4; ++r) {
        int il = ti + r * 8;
        int i  = i0 + il;
        tile[il][tw] = x[(((size_t)b * 512 + i) * 32 + h) * 32 + tw] * s[b * 512 + i];
    }
    __syncthreads();
#pragma unroll
    for (int r = 0; r < 4; ++r) {
        int wc = ti + r * 8;
        xmp[(((size_t)b * 34 + h + 1) * 34 + (wc + 1)) * 512 + i0 + tw] =
            __float2bfloat16(tile[tw][wc]);
    }
}

// ---- main conv kernel --------------------------------------------------
// grid (9 site_tiles, phase*4+o_tile, 16 b), 256 thr = 4 waves.
// M=128 o, N=128 sites, K-chunks of 32. LDS: Wl 32KB (4 taps x 128row x 32k,
// contiguous) + Xl 16KB (256 slots x 32k). XOR swizzle: LDS k-slot p holds
// global k-chunk p ^ ((row>>1)&3)  -> fragment reads are 2-way-bank only.

template <int PHASE>
__device__ __forceinline__ void conv_body(
    const __hip_bfloat16* __restrict__ wT,
    const __hip_bfloat16* __restrict__ xmp,
    const float* __restrict__ inv,
    float* __restrict__ out,
    short* Wl, short* Xl)
{
    constexpr int NT = (PHASE == 0) ? 4 : (PHASE == 3) ? 1 : 2;
    constexpr int TAPT[4][4] = {{0,2,6,8},{1,7,0,0},{3,5,0,0},{4,0,0,0}};
    constexpr int TSLT[4][4] = {{35,34,1,0},{35,1,0,0},{35,34,0,0},{35,0,0,0}};

    const int tid  = threadIdx.x;
    const int lane = tid & 63;
    const int wv   = tid >> 6;
    const int wm   = wv & 1;
    const int wn   = wv >> 1;
    const int quad = lane >> 4;
    const int c16  = lane & 15;

    const int site_tile = blockIdx.x;
    const int o_tile    = blockIdx.y & 3;
    const int b         = blockIdx.z;
    const int s0        = site_tile * 128;
    const int u_base    = s0 / 33;
    const int o_base    = o_tile * 128;

    // A fragment LDS offsets (shorts), swizzled
    int aoff[4];
#pragma unroll
    for (int a = 0; a < 4; ++a) {
        int row = wm * 64 + a * 16 + c16;
        aoff[a] = row * 32 + ((quad ^ ((row >> 1) & 3)) << 3);
    }
    // B fragment LDS offsets per (tap, f), swizzled
    int boff[NT][4];
#pragma unroll
    for (int f = 0; f < 4; ++f) {
        int site = s0 + wn * 64 + f * 16 + c16;
        int u = site / 33;
        int v = site - u * 33;
        int sb = (u - u_base) * 34 + v;
#pragma unroll
        for (int t = 0; t < NT; ++t) {
            int sl = sb + TSLT[PHASE][t];
            boff[t][f] = sl * 32 + ((quad ^ ((sl >> 1) & 3)) << 3);
        }
    }
    // staging global pointers (hoisted; add k0 per chunk)
    const __hip_bfloat16* wg[NT][2];
#pragma unroll
    for (int t = 0; t < NT; ++t) {
        const __hip_bfloat16* base =
            wT + ((size_t)TAPT[PHASE][t] * COUT + o_base) * CIN;
#pragma unroll
        for (int it = 0; it < 2; ++it) {
            int ch  = it * 256 + tid;
            int row = ch >> 2;
            int kg  = (ch & 3) ^ ((row >> 1) & 3);
            wg[t][it] = base + row * CIN + kg * 8;
        }
    }
    const __hip_bfloat16* xg[4];
#pragma unroll
    for (int it = 0; it < 4; ++it) {
        int ch   = it * 256 + tid;
        int slot = ch >> 2;
        int kg   = (ch & 3) ^ ((slot >> 1) & 3);
        int r    = slot / 34;
        int c    = slot - r * 34;
        int h1   = u_base + r;                  // padded xmp row (= h_x + 1)
        xg[it] = (slot < 204 && h1 <= 33)
                   ? xmp + (((size_t)b * 34 + h1) * 34 + c) * 512 + kg * 8
                   : xmp;                       // dummy; those slots never read
    }
    // wave-uniform LDS staging bases (shorts): chunk index base * 8
    const int wub = (tid & 192) * 8;

    floatx4 acc[4][4];
#pragma unroll
    for (int a = 0; a < 4; ++a)
#pragma unroll
        for (int f = 0; f < 4; ++f)
            acc[a][f] = (floatx4){0.f, 0.f, 0.f, 0.f};

    for (int kc = 0; kc < 16; ++kc) {
        const int k0 = kc * 32;
#pragma unroll
        for (int t = 0; t < NT; ++t)
#pragma unroll
            for (int it = 0; it < 2; ++it)
                gload16(wg[t][it] + k0, &Wl[t * 4096 + it * 2048 + wub]);
#pragma unroll
        for (int it = 0; it < 4; ++it)
            gload16(xg[it] + k0, &Xl[it * 2048 + wub]);
        __syncthreads();

#pragma unroll
        for (int t = 0; t < NT; ++t) {
            const short* wb = &Wl[t * 4096];
            short8 A0 = *(const short8*)(wb + aoff[0]);
            short8 A1 = *(const short8*)(wb + aoff[1]);
            short8 A2 = *(const short8*)(wb + aoff[2]);
            short8 A3 = *(const short8*)(wb + aoff[3]);
#pragma unroll
            for (int f = 0; f < 4; ++f) {
                short8 Bf = *(const short8*)(&Xl[boff[t][f]]);
                acc[0][f] = __builtin_amdgcn_mfma_f32_16x16x32_bf16(A0, Bf, acc[0][f], 0, 0, 0);
                acc[1][f] = __builtin_amdgcn_mfma_f32_16x16x32_bf16(A1, Bf, acc[1][f], 0, 0, 0);
                acc[2][f] = __builtin_amdgcn_mfma_f32_16x16x32_bf16(A2, Bf, acc[2][f], 0, 0, 0);
                acc[3][f] = __builtin_amdgcn_mfma_f32_16x16x32_bf16(A3, Bf, acc[3][f], 0, 0, 0);
            }
        }
        __syncthreads();
    }

    // epilogue: D col(lane&15)->site, row(quad*4+reg)->o; scale by inv[b,o]
    constexpr int py = PHASE >> 1, px = PHASE & 1;
#pragma unroll
    for (int a = 0; a < 4; ++a) {
        const int ob = o_base + wm * 64 + a * 16 + quad * 4;
        float iv[4];
#pragma unroll
        for (int r = 0; r < 4; ++r) iv[r] = inv[b * COUT + ob + r];
#pragma unroll
        for (int f = 0; f < 4; ++f) {
            int site = s0 + wn * 64 + f * 16 + c16;
            if (site < NSITE) {
                int u = site / 33;
                int v = site - u * 33;
                int y  = 2 * u + py;
                int xq = 2 * v + px;
                if (y < OW && xq < OW) {
#pragma unroll
                    for (int r = 0; r < 4; ++r)
                        out[(((size_t)b * COUT + ob + r) * OW + y) * OW + xq] =
                            acc[a][f][r] * iv[r];
                }
            }
        }
    }
}

__global__ __launch_bounds__(256, 3)
void conv_main(const __hip_bfloat16* __restrict__ wT,
               const __hip_bfloat16* __restrict__ xmp,
               const float* __restrict__ inv,
               float* __restrict__ out)
{
    __shared__ short Wl[16384];   // 32 KB: 4 taps x 128 rows x 32 k
    __shared__ short Xl[8192];    // 16 KB: 256 slots x 32 k
    const int phase = blockIdx.y >> 2;
    switch (phase) {
        case 0: conv_body<0>(wT, xmp, inv, out, Wl, Xl); break;
        case 1: conv_body<1>(wT, xmp, inv, out, Wl, Xl); break;
        case 2: conv_body<2>(wT, xmp, inv, out, Wl, Xl); break;
        default: conv_body<3>(wT, xmp, inv, out, Wl, Xl); break;
    }
}

// ---- launcher ----------------------------------------------------------
extern "C" void kernel_launch(void* const* d_in, const int* in_sizes, int n_in,
                              void* d_out, int out_size, void* d_ws, size_t ws_size,
                              hipStream_t stream)
{
    const float* x      = (const float*)d_in[0];   // (16,512,32,32)
    const float* w      = (const float*)d_in[1];   // (16,512)
    const float* weight = (const float*)d_in[2];   // (1,512,512,3,3)
    const float* lin_w  = (const float*)d_in[3];   // (512,512)
    const float* lin_b  = (const float*)d_in[4];   // (512,)
    float* out = (float*)d_out;                    // (16,512,65,65)

    char* ws = (char*)d_ws;
    float* s_buf   = (float*)(ws);                         //   32 KB
    float* inv_buf = (float*)(ws + 32768);                 //   32 KB
    float* q_buf   = (float*)(ws + 65536);                 //    1 MB
    __hip_bfloat16* wT  = (__hip_bfloat16*)(ws + 1114112); // 4.72 MB [9][512][512]
    __hip_bfloat16* xmp = (__hip_bfloat16*)(ws + 5832704); // 18.9 MB [16][34][34][512]

    k_s    <<<dim3(2, 16),      256, 0, stream>>>(w, lin_w, lin_b, s_buf);
    k_wq   <<<1024,             256, 0, stream>>>(weight, wT, q_buf);
    k_zero <<<528,              256, 0, stream>>>(xmp);
    k_inv  <<<32,               256, 0, stream>>>(s_buf, q_buf, inv_buf);
    k_xprep<<<dim3(16, 32, 16), 256, 0, stream>>>(x, s_buf, xmp);
    conv_main<<<dim3(9, 16, 16), 256, 0, stream>>>(wT, xmp, inv_buf, out);
}